// Round 3
// baseline (79.352 us; speedup 1.0000x reference)
//
#include <hip/hip_runtime.h>
#include <cfloat>
#include <cmath>

// x[B,W,L], shapelets[N,L], cls_w[1,N], cls_b[1]
constexpr int B = 64;
constexpr int W = 256;
constexpr int N = 128;
constexpr int L = 64;

// ---------------------------------------------------------------------------
// Fast kernel 1 (NCHUNKS = 16, WPB = 16): per-(b, chunk) compute
//   min_w ( ||x_w||^2 - 2 <x_w, s_n> )  for all 128 shapelets.
// ||s_n||^2 is added in kernel 2 (min commutes with the constant).
//
// Thread layout: block = 256 = 4 waves.
//   n2   = tid & 63   -> this thread owns shapelets n2 and n2+64 (reg-blocked,
//                        128 VGPRs: one LDS broadcast read feeds 8 fma)
//   slot = tid >> 6   -> wave-uniform window slot; 4 windows per slot
// ---------------------------------------------------------------------------
__global__ __launch_bounds__(256, 3) void shapelet_min16_kernel(
    const float* __restrict__ x, const float* __restrict__ shp,
    float* __restrict__ part) {
  constexpr int WPB = 16;
  __shared__ float xs[WPB * L];       // 4 KB
  __shared__ float xnorm_s[WPB];
  __shared__ float comb[4 * N];       // 2 KB

  const int b = blockIdx.x >> 4;
  const int c = blockIdx.x & 15;
  const int tid = threadIdx.x;
  const int n2 = tid & 63;
  const int slot = tid >> 6;          // wave index; uniform per wave

  // --- Stage x[b, c*16:(c+1)*16, :] into LDS: one float4 per thread, with
  // fused ||x_w||^2 via a 16-lane shuffle reduction (16 float4 per window).
  {
    const float4* xg =
        (const float4*)(x + ((size_t)b * W + (size_t)c * WPB) * L);
    float4 v = xg[tid];
    ((float4*)xs)[tid] = v;
    float p = v.x * v.x + v.y * v.y + v.z * v.z + v.w * v.w;
    p += __shfl_xor(p, 8, 16);
    p += __shfl_xor(p, 4, 16);
    p += __shfl_xor(p, 2, 16);
    p += __shfl_xor(p, 1, 16);
    if ((tid & 15) == 0) xnorm_s[tid >> 4] = p;
  }

  // --- Two shapelet rows -> 128 VGPRs (32 KB table is L1/L2-resident).
  float s0[L], s1[L];
  {
    const float4* g0 = (const float4*)(shp + (size_t)n2 * L);
    const float4* g1 = (const float4*)(shp + (size_t)(n2 + 64) * L);
#pragma unroll
    for (int i = 0; i < L / 4; ++i) {
      float4 v0 = g0[i];
      s0[4 * i + 0] = v0.x; s0[4 * i + 1] = v0.y;
      s0[4 * i + 2] = v0.z; s0[4 * i + 3] = v0.w;
      float4 v1 = g1[i];
      s1[4 * i + 0] = v1.x; s1[4 * i + 1] = v1.y;
      s1[4 * i + 2] = v1.z; s1[4 * i + 3] = v1.w;
    }
  }

  __syncthreads();

  // --- min over this slot's 4 windows; one broadcast read feeds 8 fma.
  float best0 = FLT_MAX, best1 = FLT_MAX;
  const int w0 = slot * 4;
  for (int wi = 0; wi < 4; ++wi) {
    const float* xr = xs + (size_t)(w0 + wi) * L;
    float a0 = 0.f, a1 = 0.f, b0 = 0.f, b1 = 0.f;
#pragma unroll
    for (int l = 0; l < L; l += 4) {
      // Wave-uniform address -> conflict-free LDS broadcast.
      float4 xv = *(const float4*)(xr + l);
      a0 = fmaf(xv.x, s0[l + 0], a0);
      b0 = fmaf(xv.x, s1[l + 0], b0);
      a1 = fmaf(xv.y, s0[l + 1], a1);
      b1 = fmaf(xv.y, s1[l + 1], b1);
      a0 = fmaf(xv.z, s0[l + 2], a0);
      b0 = fmaf(xv.z, s1[l + 2], b0);
      a1 = fmaf(xv.w, s0[l + 3], a1);
      b1 = fmaf(xv.w, s1[l + 3], b1);
    }
    const float xn = xnorm_s[w0 + wi];
    best0 = fminf(best0, fmaf(-2.f, a0 + a1, xn));
    best1 = fminf(best1, fmaf(-2.f, b0 + b1, xn));
  }

  // --- Combine the 4 slots per shapelet, write part[b][c][n].
  __syncthreads();
  comb[slot * N + n2] = best0;
  comb[slot * N + n2 + 64] = best1;
  __syncthreads();
  if (tid < N) {
    float m = fminf(fminf(comb[0 * N + tid], comb[1 * N + tid]),
                    fminf(comb[2 * N + tid], comb[3 * N + tid]));
    part[((size_t)b * 16 + c) * N + tid] = m;
  }
}

// ---------------------------------------------------------------------------
// Fallback kernel 1 (generic NCHUNKS) — one shapelet per thread.
// ---------------------------------------------------------------------------
template <int NCHUNKS>
__global__ __launch_bounds__(256) void shapelet_min_kernel(
    const float* __restrict__ x, const float* __restrict__ shp,
    float* __restrict__ part) {
  constexpr int WPB = W / NCHUNKS;
  constexpr int NV4 = WPB * L / 4;
  __shared__ float xs[WPB * L];
  __shared__ float xnorm_s[WPB];
  __shared__ float comb[N];

  const int b = blockIdx.x / NCHUNKS;
  const int c = blockIdx.x % NCHUNKS;
  const int tid = threadIdx.x;
  const int n = tid & (N - 1);
  const int wslot = tid >> 7;

  if (tid < WPB) xnorm_s[tid] = 0.f;
  __syncthreads();
  {
    const float4* xg =
        (const float4*)(x + ((size_t)b * W + (size_t)c * WPB) * L);
    float4* xls = (float4*)xs;
    for (int i = tid; i < NV4; i += 256) {
      float4 v = xg[i];
      xls[i] = v;
      float p = v.x * v.x + v.y * v.y + v.z * v.z + v.w * v.w;
      atomicAdd(&xnorm_s[i >> 4], p);
    }
  }

  float s[L];
  {
    const float4* sg = (const float4*)(shp + (size_t)n * L);
#pragma unroll
    for (int i = 0; i < L / 4; ++i) {
      float4 v = sg[i];
      s[4 * i + 0] = v.x; s[4 * i + 1] = v.y;
      s[4 * i + 2] = v.z; s[4 * i + 3] = v.w;
    }
  }

  __syncthreads();

  float best = FLT_MAX;
  const int w0 = wslot * (WPB / 2);
  for (int wi = 0; wi < WPB / 2; ++wi) {
    const float* xr = xs + (size_t)(w0 + wi) * L;
    float a0 = 0.f, a1 = 0.f, a2 = 0.f, a3 = 0.f;
#pragma unroll
    for (int l = 0; l < L; l += 4) {
      float4 xv = *(const float4*)(xr + l);
      a0 = fmaf(xv.x, s[l + 0], a0);
      a1 = fmaf(xv.y, s[l + 1], a1);
      a2 = fmaf(xv.z, s[l + 2], a2);
      a3 = fmaf(xv.w, s[l + 3], a3);
    }
    best = fminf(best, fmaf(-2.f, (a0 + a1) + (a2 + a3), xnorm_s[w0 + wi]));
  }

  __syncthreads();
  if (wslot == 1) comb[n] = best;
  __syncthreads();
  if (wslot == 0)
    part[((size_t)b * NCHUNKS + c) * N + n] = fminf(best, comb[n]);
}

// ---------------------------------------------------------------------------
// Kernel 2: min over chunks -> +||s_n||^2 -> sqrt -> dot(cls_w) -> sigmoid.
// grid = B, block = 128.
// ---------------------------------------------------------------------------
template <int NCHUNKS>
__global__ __launch_bounds__(128) void shapelet_head_kernel(
    const float* __restrict__ part, const float* __restrict__ shp,
    const float* __restrict__ cls_w, const float* __restrict__ cls_b,
    float* __restrict__ out) {
  const int b = blockIdx.x;
  const int n = threadIdx.x;

  float m = FLT_MAX;
#pragma unroll
  for (int c = 0; c < NCHUNKS; ++c)
    m = fminf(m, part[((size_t)b * NCHUNKS + c) * N + n]);

  float sn = 0.f;
  {
    const float4* sg = (const float4*)(shp + (size_t)n * L);
#pragma unroll
    for (int i = 0; i < L / 4; ++i) {
      float4 v = sg[i];
      sn = fmaf(v.x, v.x, sn);
      sn = fmaf(v.y, v.y, sn);
      sn = fmaf(v.z, v.z, sn);
      sn = fmaf(v.w, v.w, sn);
    }
  }

  float d2 = fmaxf(m + sn, 0.f);
  float v = sqrtf(d2) * cls_w[n];

#pragma unroll
  for (int off = 32; off > 0; off >>= 1) v += __shfl_down(v, off, 64);

  __shared__ float red[2];
  if ((n & 63) == 0) red[n >> 6] = v;
  __syncthreads();
  if (n == 0) {
    float z = red[0] + red[1] + cls_b[0];
    out[b] = 1.0f / (1.0f + expf(-z));
  }
}

template <int NCHUNKS>
static void launch_fallback(const float* x, const float* shp,
                            const float* cls_w, const float* cls_b, float* out,
                            float* part, hipStream_t stream) {
  shapelet_min_kernel<NCHUNKS><<<B * NCHUNKS, 256, 0, stream>>>(x, shp, part);
  shapelet_head_kernel<NCHUNKS>
      <<<B, 128, 0, stream>>>(part, shp, cls_w, cls_b, out);
}

extern "C" void kernel_launch(void* const* d_in, const int* in_sizes, int n_in,
                              void* d_out, int out_size, void* d_ws,
                              size_t ws_size, hipStream_t stream) {
  const float* x = (const float*)d_in[0];      // [B, W, L]
  const float* shp = (const float*)d_in[1];    // [N, L]
  const float* cls_w = (const float*)d_in[2];  // [1, N]
  const float* cls_b = (const float*)d_in[3];  // [1]
  float* out = (float*)d_out;                  // [B, 1]
  float* part = (float*)d_ws;                  // [B, NCHUNKS, N]

  const size_t per_chunk = (size_t)B * N * sizeof(float);  // 32 KB
  if (ws_size >= 16 * per_chunk) {
    shapelet_min16_kernel<<<B * 16, 256, 0, stream>>>(x, shp, part);
    shapelet_head_kernel<16>
        <<<B, 128, 0, stream>>>(part, shp, cls_w, cls_b, out);
  } else if (ws_size >= 8 * per_chunk) {
    launch_fallback<8>(x, shp, cls_w, cls_b, out, part, stream);
  } else if (ws_size >= 4 * per_chunk) {
    launch_fallback<4>(x, shp, cls_w, cls_b, out, part, stream);
  } else {
    launch_fallback<1>(x, shp, cls_w, cls_b, out, part, stream);
  }
}